// Round 11
// baseline (455.568 us; speedup 1.0000x reference)
//
#include <hip/hip_runtime.h>
#include <math.h>
#include <limits.h>

#define M_ROWS 65536   // B*N
#define DD     256
#define KC     512
#define CAP    32      // candidate list capacity per row

typedef __attribute__((ext_vector_type(8))) short bf16x8;
typedef __attribute__((ext_vector_type(4))) float f32x4;

__device__ __forceinline__ unsigned short bf16rne(float f) {
  unsigned u = __float_as_uint(f);
  return (unsigned short)((u + 0x7FFFu + ((u >> 16) & 1u)) >> 16);
}

// numpy-style pairwise sum (8 accumulators, block 128) of squares of 128 floats.
__device__ __forceinline__ float pw128_sq(const float4* __restrict__ q) {
  float r[8];
  {
    float4 a = q[0], b = q[1];
    r[0] = __fmul_rn(a.x, a.x); r[1] = __fmul_rn(a.y, a.y);
    r[2] = __fmul_rn(a.z, a.z); r[3] = __fmul_rn(a.w, a.w);
    r[4] = __fmul_rn(b.x, b.x); r[5] = __fmul_rn(b.y, b.y);
    r[6] = __fmul_rn(b.z, b.z); r[7] = __fmul_rn(b.w, b.w);
  }
#pragma unroll
  for (int i = 2; i < 32; i += 2) {
    float4 a = q[i], b = q[i + 1];
    r[0] = __fadd_rn(r[0], __fmul_rn(a.x, a.x));
    r[1] = __fadd_rn(r[1], __fmul_rn(a.y, a.y));
    r[2] = __fadd_rn(r[2], __fmul_rn(a.z, a.z));
    r[3] = __fadd_rn(r[3], __fmul_rn(a.w, a.w));
    r[4] = __fadd_rn(r[4], __fmul_rn(b.x, b.x));
    r[5] = __fadd_rn(r[5], __fmul_rn(b.y, b.y));
    r[6] = __fadd_rn(r[6], __fmul_rn(b.z, b.z));
    r[7] = __fadd_rn(r[7], __fmul_rn(b.w, b.w));
  }
  return __fadd_rn(__fadd_rn(__fadd_rn(r[0], r[1]), __fadd_rn(r[2], r[3])),
                   __fadd_rn(__fadd_rn(r[4], r[5]), __fadd_rn(r[6], r[7])));
}

__global__ void sumsq_kernel(const float* __restrict__ x, float* __restrict__ s,
                             int nrows) {
  int r = blockIdx.x * blockDim.x + threadIdx.x;
  if (r >= nrows) return;
  const float4* q = (const float4*)(x + (size_t)r * DD);
  s[r] = __fadd_rn(pw128_sq(q), pw128_sq(q + 32));
}

// async global->LDS, 16B/lane
typedef __attribute__((address_space(1))) const void gas_void;
typedef __attribute__((address_space(3))) void las_void;
__device__ __forceinline__ void gl_lds16(const void* g, void* l) {
  __builtin_amdgcn_global_load_lds((gas_void*)g, (las_void*)l, 16, 0, 0);
}

// Build the pre-swizzled bf16 B-image: img[s][c][x] (16B units) holds k-unit
// u = x ^ ((c>>1)&3) of code c, slice s (k = s*32 + u*8 .. +7). Slice 8 is the
// K-extension carrying se (so the MFMA directly yields -2*dot + se).
__global__ void build_img_kernel(const float* __restrict__ cb,
                                 const float* __restrict__ se,
                                 unsigned short* __restrict__ img) {
  int u0 = blockIdx.x * 256 + threadIdx.x;
  if (u0 >= 9 * KC * 4) return;
  int x = u0 & 3, c = (u0 >> 2) & (KC - 1), s = u0 >> 11;
  int u = x ^ ((c >> 1) & 3);
  unsigned short o[8];
  if (s < 8) {
    const float* src = cb + (size_t)c * DD + s * 32 + u * 8;
#pragma unroll
    for (int j = 0; j < 8; ++j) o[j] = bf16rne(src[j]);
  } else {
#pragma unroll
    for (int j = 0; j < 8; ++j) o[j] = 0;
    if (u == 0) o[0] = bf16rne(se[c]);
  }
  uint4 w;
  w.x = (unsigned)o[0] | ((unsigned)o[1] << 16);
  w.y = (unsigned)o[2] | ((unsigned)o[3] << 16);
  w.z = (unsigned)o[4] | ((unsigned)o[5] << 16);
  w.w = (unsigned)o[6] | ((unsigned)o[7] << 16);
  *(uint4*)(img + (size_t)u0 * 8) = w;
}

// MFMA filter: block = 4 waves x 16 rows = 64 rows, all 512 codes, K=288
// (256 + se extension). A = bf16(-2*z) in VGPR frags; B staged per-slice via
// global_load_lds from the pre-swizzled image. acc = g_apx = -2*dot + se.
// Per-row min + margin -> candidate codes appended to global lists.
// Margin soundness: |g_apx-g| <= 2^-7*2.01*||z||*||e|| + 2e-5, ||e|| < 0.03125
// => needed ~4.9e-4*sqrt(s_r); used 1.6e-3*sqrt(s_r)+1e-3 (3x headroom).
__global__ __launch_bounds__(256) void filter_kernel(
    const float* __restrict__ z, const unsigned short* __restrict__ img,
    const float* __restrict__ s, int* __restrict__ cnt_g,
    unsigned short* __restrict__ cands) {
  __shared__ unsigned short b_lds[KC * 32];   // 512 codes x 4 units x 16B = 32KB
  __shared__ int cnt_lds[64];

  const int tid = threadIdx.x;
  const int lane = tid & 63, wv = tid >> 6;
  const int lx = lane & 15, g = lane >> 4;
  const int rowbase = blockIdx.x * 64;

  if (tid < 64) cnt_lds[tid] = 0;

  // A fragments (lane: row = wv*16+lx, k = s*32 + g*8 + j), scaled by -2
  bf16x8 afrag[9];
  {
    const float* zrow = z + (size_t)(rowbase + wv * 16 + lx) * DD;
#pragma unroll
    for (int s8 = 0; s8 < 8; ++s8) {
      const float4* p = (const float4*)(zrow + s8 * 32 + g * 8);
      float4 x0 = p[0], x1 = p[1];
      bf16x8 a;
      a[0] = (short)bf16rne(-2.0f * x0.x); a[1] = (short)bf16rne(-2.0f * x0.y);
      a[2] = (short)bf16rne(-2.0f * x0.z); a[3] = (short)bf16rne(-2.0f * x0.w);
      a[4] = (short)bf16rne(-2.0f * x1.x); a[5] = (short)bf16rne(-2.0f * x1.y);
      a[6] = (short)bf16rne(-2.0f * x1.z); a[7] = (short)bf16rne(-2.0f * x1.w);
      afrag[s8] = a;
    }
    bf16x8 a;
#pragma unroll
    for (int j = 0; j < 8; ++j) a[j] = 0;
    if (g == 0) a[0] = (short)0x3F80;   // bf16(1.0): ext column of A
    afrag[8] = a;
  }

  f32x4 acc[32];
#pragma unroll
  for (int t = 0; t < 32; ++t) acc[t] = (f32x4){0.f, 0.f, 0.f, 0.f};

  const int bbase = lx * 4 + (g ^ ((lx >> 1) & 3));   // unit idx of B frag
  const bf16x8* bunit = (const bf16x8*)b_lds;

#pragma unroll   // full unroll keeps afrag[ss] statically indexed (no scratch)
  for (int ss = 0; ss < 9; ++ss) {
    __syncthreads();   // prev slice consumed (and cnt_lds init on ss=0)
#pragma unroll
    for (int seg = 0; seg < 8; ++seg) {
      gl_lds16((const char*)img + ((size_t)ss * 2048 + seg * 256 + tid) * 16,
               (char*)b_lds + (seg * 256 + wv * 64) * 16);
    }
    __syncthreads();   // staged slice visible (vmcnt drained by barrier)
    bf16x8 av = afrag[ss];
#pragma unroll
    for (int t = 0; t < 32; ++t)
      acc[t] = __builtin_amdgcn_mfma_f32_16x16x32_bf16(
          av, bunit[t * 64 + bbase], acc[t], 0, 0, 0);
  }

  // C layout (m89-verified): col(code-in-tile)=lane&15, row=4*(lane>>4)+reg.
  const unsigned long long gmask = 0xFFFFULL << (g * 16);
  const unsigned long long below = (1ULL << lane) - 1;
#pragma unroll
  for (int q = 0; q < 4; ++q) {
    float m = acc[0][q];
#pragma unroll
    for (int t = 1; t < 32; ++t) m = fminf(m, acc[t][q]);
#pragma unroll
    for (int off = 1; off < 16; off <<= 1)
      m = fminf(m, __shfl_xor(m, off, 64));
    const int r_loc = wv * 16 + 4 * g + q;
    const float sr = s[rowbase + r_loc];
    const float thr = m + 1.6e-3f * sqrtf(sr) + 1e-3f;
#pragma unroll
    for (int t = 0; t < 32; ++t) {
      bool keep = (acc[t][q] <= thr);
      unsigned long long mask = __ballot(keep);
      if (keep) {
        unsigned long long mym = mask & gmask;
        int prefix = __popcll(mym & below);
        unsigned long long lowbit = mym & (0ULL - mym);
        int low = __popcll(lowbit - 1);
        int base = 0;
        if (lane == low) base = atomicAdd(&cnt_lds[r_loc], __popcll(mym));
        base = __shfl(base, low, 64);
        int off2 = base + prefix;
        if (off2 < CAP)
          cands[(size_t)(rowbase + r_loc) * CAP + off2] =
              (unsigned short)(t * 16 + lx);
      }
    }
  }
  __syncthreads();
  if (tid < 64) cnt_g[rowbase + tid] = cnt_lds[tid];
}

// Exact rescore + outputs: one wave per row. Candidates get the bit-identical
// reference chain: acc=0; k ascending fma; d = fl(fl(s-2*dot)+se); lex (d,code)
// min. Reference argmin is in the candidate set (margin proof) => exact.
__global__ __launch_bounds__(256) void rescore_kernel(
    const float* __restrict__ z, const float* __restrict__ cb,
    const float* __restrict__ s, const float* __restrict__ se,
    const int* __restrict__ cnt_g, const unsigned short* __restrict__ cands,
    float* __restrict__ out) {
  const int tid = threadIdx.x;
  const int lane = tid & 63, wv = tid >> 6;
  const int r = blockIdx.x * 4 + wv;
  const float4* zr = (const float4*)(z + (size_t)r * DD);
  const float s_r = s[r];
  const int cnt = cnt_g[r];
  float bd = INFINITY;
  int bi = INT_MAX;

  if (cnt <= CAP) {                       // normal path: one candidate/lane
    const bool act = lane < cnt;
    const int code = act ? (int)cands[(size_t)r * CAP + lane] : 0;
    const float4* cr = (const float4*)(cb + (size_t)code * DD);
    float a = 0.0f;
#pragma unroll 8
    for (int k4 = 0; k4 < 64; ++k4) {
      float4 zf = zr[k4], cf = cr[k4];
      a = __fmaf_rn(zf.x, cf.x, a);
      a = __fmaf_rn(zf.y, cf.y, a);
      a = __fmaf_rn(zf.z, cf.z, a);
      a = __fmaf_rn(zf.w, cf.w, a);
    }
    float d = __fadd_rn(__fsub_rn(s_r, __fmul_rn(2.0f, a)), se[code]);
    if (act) { bd = d; bi = code; }
  } else {                                // overflow fallback: scan all codes
#pragma unroll 1
    for (int j = 0; j < 8; ++j) {
      int code = lane + 64 * j;
      const float4* cr = (const float4*)(cb + (size_t)code * DD);
      float a = 0.0f;
#pragma unroll 4
      for (int k4 = 0; k4 < 64; ++k4) {
        float4 zf = zr[k4], cf = cr[k4];
        a = __fmaf_rn(zf.x, cf.x, a);
        a = __fmaf_rn(zf.y, cf.y, a);
        a = __fmaf_rn(zf.z, cf.z, a);
        a = __fmaf_rn(zf.w, cf.w, a);
      }
      float d = __fadd_rn(__fsub_rn(s_r, __fmul_rn(2.0f, a)), se[code]);
      if (d < bd || (d == bd && code < bi)) { bd = d; bi = code; }
    }
  }
#pragma unroll
  for (int off = 1; off < 64; off <<= 1) {
    float od = __shfl_xor(bd, off, 64);
    int oi = __shfl_xor(bi, off, 64);
    if (od < bd || (od == bd && oi < bi)) { bd = od; bi = oi; }
  }
  if (bi > KC - 1) bi = 0;   // safety; unreachable (cnt >= 1 by construction)

  const float4* cbest = (const float4*)(cb + (size_t)bi * DD);
  float4 zv = zr[lane], cv = cbest[lane];
  float4 o0;
  o0.x = __fadd_rn(zv.x, __fsub_rn(cv.x, zv.x));
  o0.y = __fadd_rn(zv.y, __fsub_rn(cv.y, zv.y));
  o0.z = __fadd_rn(zv.z, __fsub_rn(cv.z, zv.z));
  o0.w = __fadd_rn(zv.w, __fsub_rn(cv.w, zv.w));
  float4* out0 = (float4*)out;
  float4* out1 = out0 + (size_t)M_ROWS * 64;
  out0[(size_t)r * 64 + lane] = o0;
  out1[(size_t)r * 64 + lane] = cv;
}

extern "C" void kernel_launch(void* const* d_in, const int* in_sizes, int n_in,
                              void* d_out, int out_size, void* d_ws, size_t ws_size,
                              hipStream_t stream) {
  const float* z  = (const float*)d_in[0];   // [65536, 256]
  const float* cb = (const float*)d_in[1];   // [512, 256]
  float* out = (float*)d_out;

  // ws layout (bytes): s 0..262144 | se ..264192 | img ..559104 (294912)
  //                    cnt ..821248 (262144) | cands ..5015552 (4 MB)
  float* s  = (float*)d_ws;
  float* se = s + M_ROWS;
  unsigned short* img = (unsigned short*)(se + KC);
  int* cnt = (int*)((char*)d_ws + 559104);
  unsigned short* cands = (unsigned short*)((char*)d_ws + 821248);

  sumsq_kernel<<<M_ROWS / 256, 256, 0, stream>>>(z, s, M_ROWS);
  sumsq_kernel<<<KC / 256, 256, 0, stream>>>(cb, se, KC);
  build_img_kernel<<<(9 * KC * 4 + 255) / 256, 256, 0, stream>>>(cb, se, img);
  filter_kernel<<<M_ROWS / 64, 256, 0, stream>>>(z, img, s, cnt, cands);
  rescore_kernel<<<M_ROWS / 4, 256, 0, stream>>>(z, cb, s, se, cnt, cands, out);
}

// Round 12
// 454.494 us; speedup vs baseline: 1.0024x; 1.0024x over previous
//
#include <hip/hip_runtime.h>
#include <math.h>
#include <limits.h>

#define M_ROWS 65536   // B*N
#define DD     256
#define KC     512
#define CAP    32      // candidate list capacity per row

typedef __attribute__((ext_vector_type(8))) short bf16x8;
typedef __attribute__((ext_vector_type(4))) float f32x4;

__device__ __forceinline__ unsigned short bf16rne(float f) {
  unsigned u = __float_as_uint(f);
  return (unsigned short)((u + 0x7FFFu + ((u >> 16) & 1u)) >> 16);
}

// numpy-style pairwise sum (8 accumulators, block 128) of squares of 128 floats.
__device__ __forceinline__ float pw128_sq(const float4* __restrict__ q) {
  float r[8];
  {
    float4 a = q[0], b = q[1];
    r[0] = __fmul_rn(a.x, a.x); r[1] = __fmul_rn(a.y, a.y);
    r[2] = __fmul_rn(a.z, a.z); r[3] = __fmul_rn(a.w, a.w);
    r[4] = __fmul_rn(b.x, b.x); r[5] = __fmul_rn(b.y, b.y);
    r[6] = __fmul_rn(b.z, b.z); r[7] = __fmul_rn(b.w, b.w);
  }
#pragma unroll
  for (int i = 2; i < 32; i += 2) {
    float4 a = q[i], b = q[i + 1];
    r[0] = __fadd_rn(r[0], __fmul_rn(a.x, a.x));
    r[1] = __fadd_rn(r[1], __fmul_rn(a.y, a.y));
    r[2] = __fadd_rn(r[2], __fmul_rn(a.z, a.z));
    r[3] = __fadd_rn(r[3], __fmul_rn(a.w, a.w));
    r[4] = __fadd_rn(r[4], __fmul_rn(b.x, b.x));
    r[5] = __fadd_rn(r[5], __fmul_rn(b.y, b.y));
    r[6] = __fadd_rn(r[6], __fmul_rn(b.z, b.z));
    r[7] = __fadd_rn(r[7], __fmul_rn(b.w, b.w));
  }
  return __fadd_rn(__fadd_rn(__fadd_rn(r[0], r[1]), __fadd_rn(r[2], r[3])),
                   __fadd_rn(__fadd_rn(r[4], r[5]), __fadd_rn(r[6], r[7])));
}

__global__ void sumsq_kernel(const float* __restrict__ x, float* __restrict__ s,
                             int nrows) {
  int r = blockIdx.x * blockDim.x + threadIdx.x;
  if (r >= nrows) return;
  const float4* q = (const float4*)(x + (size_t)r * DD);
  s[r] = __fadd_rn(pw128_sq(q), pw128_sq(q + 32));
}

// async global->LDS, 16B/lane
typedef __attribute__((address_space(1))) const void gas_void;
typedef __attribute__((address_space(3))) void las_void;
__device__ __forceinline__ void gl_lds16(const void* g, void* l) {
  __builtin_amdgcn_global_load_lds((gas_void*)g, (las_void*)l, 16, 0, 0);
}

// Build the pre-swizzled bf16 B-image: img[s][c][x] (16B units) holds k-unit
// u = x ^ ((c>>1)&3) of code c, slice s (k = s*32 + u*8 .. +7). Slice 8 is the
// K-extension carrying se (so the MFMA directly yields -2*dot + se).
__global__ void build_img_kernel(const float* __restrict__ cb,
                                 const float* __restrict__ se,
                                 unsigned short* __restrict__ img) {
  int u0 = blockIdx.x * 256 + threadIdx.x;
  if (u0 >= 9 * KC * 4) return;
  int x = u0 & 3, c = (u0 >> 2) & (KC - 1), s = u0 >> 11;
  int u = x ^ ((c >> 1) & 3);
  unsigned short o[8];
  if (s < 8) {
    const float* src = cb + (size_t)c * DD + s * 32 + u * 8;
#pragma unroll
    for (int j = 0; j < 8; ++j) o[j] = bf16rne(src[j]);
  } else {
#pragma unroll
    for (int j = 0; j < 8; ++j) o[j] = 0;
    if (u == 0) o[0] = bf16rne(se[c]);
  }
  uint4 w;
  w.x = (unsigned)o[0] | ((unsigned)o[1] << 16);
  w.y = (unsigned)o[2] | ((unsigned)o[3] << 16);
  w.z = (unsigned)o[4] | ((unsigned)o[5] << 16);
  w.w = (unsigned)o[6] | ((unsigned)o[7] << 16);
  *(uint4*)(img + (size_t)u0 * 8) = w;
}

// MFMA filter: block = 4 waves x 16 rows = 64 rows, all 512 codes, K=288
// (256 + se extension). A = bf16(-2*z) in VGPR frags; B staged per-slice via
// global_load_lds from the pre-swizzled image. acc = g_apx = -2*dot + se.
// Per-row min + margin -> candidate codes appended to global lists.
// Margin soundness: |g_apx-g| <= 2^-7*2.01*||z||*||e|| + 2e-5, ||e|| < 0.03125
// => needed ~4.9e-4*sqrt(s_r); used 1.6e-3*sqrt(s_r)+1e-3 (3x headroom).
__global__ __launch_bounds__(256) void filter_kernel(
    const float* __restrict__ z, const unsigned short* __restrict__ img,
    const float* __restrict__ s, int* __restrict__ cnt_g,
    unsigned short* __restrict__ cands) {
  __shared__ unsigned short b_lds[KC * 32];   // 512 codes x 4 units x 16B = 32KB
  __shared__ int cnt_lds[64];

  const int tid = threadIdx.x;
  const int lane = tid & 63, wv = tid >> 6;
  const int lx = lane & 15, g = lane >> 4;
  const int rowbase = blockIdx.x * 64;

  if (tid < 64) cnt_lds[tid] = 0;

  // A fragments (lane: row = wv*16+lx, k = s*32 + g*8 + j), scaled by -2
  bf16x8 afrag[9];
  {
    const float* zrow = z + (size_t)(rowbase + wv * 16 + lx) * DD;
#pragma unroll
    for (int s8 = 0; s8 < 8; ++s8) {
      const float4* p = (const float4*)(zrow + s8 * 32 + g * 8);
      float4 x0 = p[0], x1 = p[1];
      bf16x8 a;
      a[0] = (short)bf16rne(-2.0f * x0.x); a[1] = (short)bf16rne(-2.0f * x0.y);
      a[2] = (short)bf16rne(-2.0f * x0.z); a[3] = (short)bf16rne(-2.0f * x0.w);
      a[4] = (short)bf16rne(-2.0f * x1.x); a[5] = (short)bf16rne(-2.0f * x1.y);
      a[6] = (short)bf16rne(-2.0f * x1.z); a[7] = (short)bf16rne(-2.0f * x1.w);
      afrag[s8] = a;
    }
    bf16x8 a;
#pragma unroll
    for (int j = 0; j < 8; ++j) a[j] = 0;
    if (g == 0) a[0] = (short)0x3F80;   // bf16(1.0): ext column of A
    afrag[8] = a;
  }

  f32x4 acc[32];
#pragma unroll
  for (int t = 0; t < 32; ++t) acc[t] = (f32x4){0.f, 0.f, 0.f, 0.f};

  const int bbase = lx * 4 + (g ^ ((lx >> 1) & 3));   // unit idx of B frag
  const bf16x8* bunit = (const bf16x8*)b_lds;

#pragma unroll   // full unroll keeps afrag[ss] statically indexed (no scratch)
  for (int ss = 0; ss < 9; ++ss) {
    __syncthreads();   // prev slice consumed (and cnt_lds init on ss=0)
#pragma unroll
    for (int seg = 0; seg < 8; ++seg) {
      gl_lds16((const char*)img + ((size_t)ss * 2048 + seg * 256 + tid) * 16,
               (char*)b_lds + (seg * 256 + wv * 64) * 16);
    }
    __syncthreads();   // staged slice visible (vmcnt drained by barrier)
    bf16x8 av = afrag[ss];
#pragma unroll
    for (int t = 0; t < 32; ++t)
      acc[t] = __builtin_amdgcn_mfma_f32_16x16x32_bf16(
          av, bunit[t * 64 + bbase], acc[t], 0, 0, 0);
  }

  // C layout (m89-verified): col(code-in-tile)=lane&15, row=4*(lane>>4)+reg.
  const unsigned long long gmask = 0xFFFFULL << (g * 16);
  const unsigned long long below = (1ULL << lane) - 1;
#pragma unroll
  for (int q = 0; q < 4; ++q) {
    float m = acc[0][q];
#pragma unroll
    for (int t = 1; t < 32; ++t) m = fminf(m, acc[t][q]);
#pragma unroll
    for (int off = 1; off < 16; off <<= 1)
      m = fminf(m, __shfl_xor(m, off, 64));
    const int r_loc = wv * 16 + 4 * g + q;
    const float sr = s[rowbase + r_loc];
    const float thr = m + 1.6e-3f * sqrtf(sr) + 1e-3f;
#pragma unroll
    for (int t = 0; t < 32; ++t) {
      bool keep = (acc[t][q] <= thr);
      unsigned long long mask = __ballot(keep);
      if (keep) {
        unsigned long long mym = mask & gmask;
        int prefix = __popcll(mym & below);
        unsigned long long lowbit = mym & (0ULL - mym);
        int low = __popcll(lowbit - 1);
        int base = 0;
        if (lane == low) base = atomicAdd(&cnt_lds[r_loc], __popcll(mym));
        base = __shfl(base, low, 64);
        int off2 = base + prefix;
        if (off2 < CAP)
          cands[(size_t)(rowbase + r_loc) * CAP + off2] =
              (unsigned short)(t * 16 + lx);
      }
    }
  }
  __syncthreads();
  if (tid < 64) cnt_g[rowbase + tid] = cnt_lds[tid];
}

// Exact rescore + outputs: one wave per row. Candidates get the bit-identical
// reference chain: acc=0; k ascending fma; d = fl(fl(s-2*dot)+se); lex (d,code)
// min. Reference argmin is in the candidate set (margin proof) => exact.
__global__ __launch_bounds__(256) void rescore_kernel(
    const float* __restrict__ z, const float* __restrict__ cb,
    const float* __restrict__ s, const float* __restrict__ se,
    const int* __restrict__ cnt_g, const unsigned short* __restrict__ cands,
    float* __restrict__ out) {
  const int tid = threadIdx.x;
  const int lane = tid & 63, wv = tid >> 6;
  const int r = blockIdx.x * 4 + wv;
  const float4* zr = (const float4*)(z + (size_t)r * DD);
  const float s_r = s[r];
  const int cnt = cnt_g[r];
  float bd = INFINITY;
  int bi = INT_MAX;

  if (cnt <= CAP) {                       // normal path: one candidate/lane
    const bool act = lane < cnt;
    const int code = act ? (int)cands[(size_t)r * CAP + lane] : 0;
    const float4* cr = (const float4*)(cb + (size_t)code * DD);
    float a = 0.0f;
#pragma unroll 8
    for (int k4 = 0; k4 < 64; ++k4) {
      float4 zf = zr[k4], cf = cr[k4];
      a = __fmaf_rn(zf.x, cf.x, a);
      a = __fmaf_rn(zf.y, cf.y, a);
      a = __fmaf_rn(zf.z, cf.z, a);
      a = __fmaf_rn(zf.w, cf.w, a);
    }
    float d = __fadd_rn(__fsub_rn(s_r, __fmul_rn(2.0f, a)), se[code]);
    if (act) { bd = d; bi = code; }
  } else {                                // overflow fallback: scan all codes
#pragma unroll 1
    for (int j = 0; j < 8; ++j) {
      int code = lane + 64 * j;
      const float4* cr = (const float4*)(cb + (size_t)code * DD);
      float a = 0.0f;
#pragma unroll 4
      for (int k4 = 0; k4 < 64; ++k4) {
        float4 zf = zr[k4], cf = cr[k4];
        a = __fmaf_rn(zf.x, cf.x, a);
        a = __fmaf_rn(zf.y, cf.y, a);
        a = __fmaf_rn(zf.z, cf.z, a);
        a = __fmaf_rn(zf.w, cf.w, a);
      }
      float d = __fadd_rn(__fsub_rn(s_r, __fmul_rn(2.0f, a)), se[code]);
      if (d < bd || (d == bd && code < bi)) { bd = d; bi = code; }
    }
  }
#pragma unroll
  for (int off = 1; off < 64; off <<= 1) {
    float od = __shfl_xor(bd, off, 64);
    int oi = __shfl_xor(bi, off, 64);
    if (od < bd || (od == bd && oi < bi)) { bd = od; bi = oi; }
  }
  if (bi > KC - 1) bi = 0;   // safety; unreachable (cnt >= 1 by construction)

  const float4* cbest = (const float4*)(cb + (size_t)bi * DD);
  float4 zv = zr[lane], cv = cbest[lane];
  float4 o0;
  o0.x = __fadd_rn(zv.x, __fsub_rn(cv.x, zv.x));
  o0.y = __fadd_rn(zv.y, __fsub_rn(cv.y, zv.y));
  o0.z = __fadd_rn(zv.z, __fsub_rn(cv.z, zv.z));
  o0.w = __fadd_rn(zv.w, __fsub_rn(cv.w, zv.w));
  float4* out0 = (float4*)out;
  float4* out1 = out0 + (size_t)M_ROWS * 64;
  out0[(size_t)r * 64 + lane] = o0;
  out1[(size_t)r * 64 + lane] = cv;
}

extern "C" void kernel_launch(void* const* d_in, const int* in_sizes, int n_in,
                              void* d_out, int out_size, void* d_ws, size_t ws_size,
                              hipStream_t stream) {
  const float* z  = (const float*)d_in[0];   // [65536, 256]
  const float* cb = (const float*)d_in[1];   // [512, 256]
  float* out = (float*)d_out;

  // ws layout (bytes): s 0..262144 | se ..264192 | img ..559104 (294912)
  //                    cnt ..821248 (262144) | cands ..5015552 (4 MB)
  float* s  = (float*)d_ws;
  float* se = s + M_ROWS;
  unsigned short* img = (unsigned short*)(se + KC);
  int* cnt = (int*)((char*)d_ws + 559104);
  unsigned short* cands = (unsigned short*)((char*)d_ws + 821248);

  sumsq_kernel<<<M_ROWS / 256, 256, 0, stream>>>(z, s, M_ROWS);
  sumsq_kernel<<<KC / 256, 256, 0, stream>>>(cb, se, KC);
  build_img_kernel<<<(9 * KC * 4 + 255) / 256, 256, 0, stream>>>(cb, se, img);
  filter_kernel<<<M_ROWS / 64, 256, 0, stream>>>(z, img, s, cnt, cands);
  rescore_kernel<<<M_ROWS / 4, 256, 0, stream>>>(z, cb, s, se, cnt, cands, out);
}

// Round 13
// 438.931 us; speedup vs baseline: 1.0379x; 1.0355x over previous
//
#include <hip/hip_runtime.h>
#include <math.h>
#include <limits.h>

#define M_ROWS 65536   // B*N
#define DD     256
#define KC     512
#define CAP    32      // per-row candidate cap before overflow fallback

typedef __attribute__((ext_vector_type(8))) short bf16x8;
typedef __attribute__((ext_vector_type(4))) float f32x4;

__device__ __forceinline__ unsigned short bf16rne(float f) {
  unsigned u = __float_as_uint(f);
  return (unsigned short)((u + 0x7FFFu + ((u >> 16) & 1u)) >> 16);
}

// order-preserving f32 -> u32 (uint ascending == float ascending)
__device__ __forceinline__ unsigned ford(float f) {
  unsigned b = __float_as_uint(f);
  return (b & 0x80000000u) ? ~b : (b | 0x80000000u);
}

// numpy-style pairwise sum (8 accumulators, block 128) of squares of 128 floats.
__device__ __forceinline__ float pw128_sq(const float4* __restrict__ q) {
  float r[8];
  {
    float4 a = q[0], b = q[1];
    r[0] = __fmul_rn(a.x, a.x); r[1] = __fmul_rn(a.y, a.y);
    r[2] = __fmul_rn(a.z, a.z); r[3] = __fmul_rn(a.w, a.w);
    r[4] = __fmul_rn(b.x, b.x); r[5] = __fmul_rn(b.y, b.y);
    r[6] = __fmul_rn(b.z, b.z); r[7] = __fmul_rn(b.w, b.w);
  }
#pragma unroll
  for (int i = 2; i < 32; i += 2) {
    float4 a = q[i], b = q[i + 1];
    r[0] = __fadd_rn(r[0], __fmul_rn(a.x, a.x));
    r[1] = __fadd_rn(r[1], __fmul_rn(a.y, a.y));
    r[2] = __fadd_rn(r[2], __fmul_rn(a.z, a.z));
    r[3] = __fadd_rn(r[3], __fmul_rn(a.w, a.w));
    r[4] = __fadd_rn(r[4], __fmul_rn(b.x, b.x));
    r[5] = __fadd_rn(r[5], __fmul_rn(b.y, b.y));
    r[6] = __fadd_rn(r[6], __fmul_rn(b.z, b.z));
    r[7] = __fadd_rn(r[7], __fmul_rn(b.w, b.w));
  }
  return __fadd_rn(__fadd_rn(__fadd_rn(r[0], r[1]), __fadd_rn(r[2], r[3])),
                   __fadd_rn(__fadd_rn(r[4], r[5]), __fadd_rn(r[6], r[7])));
}

__global__ void sumsq_kernel(const float* __restrict__ x, float* __restrict__ s,
                             int nrows) {
  int r = blockIdx.x * blockDim.x + threadIdx.x;
  if (r >= nrows) return;
  const float4* q = (const float4*)(x + (size_t)r * DD);
  s[r] = __fadd_rn(pw128_sq(q), pw128_sq(q + 32));
}

__global__ void init_kernel(unsigned long long* __restrict__ rowkey,
                            unsigned* __restrict__ qn,
                            unsigned* __restrict__ ovn) {
  int i = blockIdx.x * 256 + threadIdx.x;
  rowkey[i] = ~0ull;
  if (i == 0) { *qn = 0; *ovn = 0; }
}

// async global->LDS, 16B/lane
typedef __attribute__((address_space(1))) const void gas_void;
typedef __attribute__((address_space(3))) void las_void;
__device__ __forceinline__ void gl_lds16(const void* g, void* l) {
  __builtin_amdgcn_global_load_lds((gas_void*)g, (las_void*)l, 16, 0, 0);
}

// Pre-swizzled bf16 B-image: img[s][c][x] (16B units) holds k-unit
// u = x ^ ((c>>1)&3) of code c, slice s. Slice 8 = K-extension carrying se.
__global__ void build_img_kernel(const float* __restrict__ cb,
                                 const float* __restrict__ se,
                                 unsigned short* __restrict__ img) {
  int u0 = blockIdx.x * 256 + threadIdx.x;
  if (u0 >= 9 * KC * 4) return;
  int x = u0 & 3, c = (u0 >> 2) & (KC - 1), s = u0 >> 11;
  int u = x ^ ((c >> 1) & 3);
  unsigned short o[8];
  if (s < 8) {
    const float* src = cb + (size_t)c * DD + s * 32 + u * 8;
#pragma unroll
    for (int j = 0; j < 8; ++j) o[j] = bf16rne(src[j]);
  } else {
#pragma unroll
    for (int j = 0; j < 8; ++j) o[j] = 0;
    if (u == 0) o[0] = bf16rne(se[c]);
  }
  uint4 w;
  w.x = (unsigned)o[0] | ((unsigned)o[1] << 16);
  w.y = (unsigned)o[2] | ((unsigned)o[3] << 16);
  w.z = (unsigned)o[4] | ((unsigned)o[5] << 16);
  w.w = (unsigned)o[6] | ((unsigned)o[7] << 16);
  *(uint4*)(img + (size_t)u0 * 8) = w;
}

// MFMA filter (double-buffered B staging): block = 64 rows x 512 codes, K=288.
// acc = g_apx = -2*dot + se (bf16 MFMA). Per-row min + sound margin ->
// candidates appended to a global queue via LDS buffering.
// Margin: |g_apx-g| <= 2^-8*2*||z||*||e||, ||e|| <= 0.03125 => need
// ~4.9e-4*sqrt(s_r); used 1.6e-3*sqrt(s_r)+1e-3 (3x headroom).
__global__ __launch_bounds__(256) void filter_kernel(
    const float* __restrict__ z, const unsigned short* __restrict__ img,
    const float* __restrict__ s, unsigned* __restrict__ qn,
    unsigned* __restrict__ queue, unsigned qcap,
    unsigned* __restrict__ ovn, unsigned* __restrict__ ovf) {
  __shared__ unsigned short b_lds[2][KC * 32];  // 2 x 32 KB
  __shared__ int cnt_lds[64];
  __shared__ unsigned lds_q[64 * CAP];          // 8 KB
  __shared__ int q_cnt;
  __shared__ unsigned gbase_s;
  __shared__ int qof;

  const int tid = threadIdx.x;
  const int lane = tid & 63, wv = tid >> 6;
  const int lx = lane & 15, g = lane >> 4;
  const int rowbase = blockIdx.x * 64;

  if (tid < 64) cnt_lds[tid] = 0;
  if (tid == 0) q_cnt = 0;

  // A fragments (lane: row = wv*16+lx, k = ss*32 + g*8 + j), scaled by -2
  bf16x8 afrag[9];
  {
    const float* zrow = z + (size_t)(rowbase + wv * 16 + lx) * DD;
#pragma unroll
    for (int s8 = 0; s8 < 8; ++s8) {
      const float4* p = (const float4*)(zrow + s8 * 32 + g * 8);
      float4 x0 = p[0], x1 = p[1];
      bf16x8 a;
      a[0] = (short)bf16rne(-2.0f * x0.x); a[1] = (short)bf16rne(-2.0f * x0.y);
      a[2] = (short)bf16rne(-2.0f * x0.z); a[3] = (short)bf16rne(-2.0f * x0.w);
      a[4] = (short)bf16rne(-2.0f * x1.x); a[5] = (short)bf16rne(-2.0f * x1.y);
      a[6] = (short)bf16rne(-2.0f * x1.z); a[7] = (short)bf16rne(-2.0f * x1.w);
      afrag[s8] = a;
    }
    bf16x8 a;
#pragma unroll
    for (int j = 0; j < 8; ++j) a[j] = 0;
    if (g == 0) a[0] = (short)0x3F80;   // bf16(1.0): ext column of A
    afrag[8] = a;
  }

  f32x4 acc[32];
#pragma unroll
  for (int t = 0; t < 32; ++t) acc[t] = (f32x4){0.f, 0.f, 0.f, 0.f};

  const int bbase = lx * 4 + (g ^ ((lx >> 1) & 3));

  auto stage = [&](int buf, int ss) {
#pragma unroll
    for (int seg = 0; seg < 8; ++seg) {
      gl_lds16((const char*)img + ((size_t)ss * 2048 + seg * 256 + tid) * 16,
               (char*)&b_lds[buf][0] + (seg * 256 + wv * 64) * 16);
    }
  };

  stage(0, 0);
  __syncthreads();   // slice 0 visible; cnt/q_cnt init published
#pragma unroll       // full unroll: afrag[ss] statically indexed
  for (int ss = 0; ss < 9; ++ss) {
    if (ss < 8) stage((ss + 1) & 1, ss + 1);   // prefetch next slice
    bf16x8 av = afrag[ss];
    const bf16x8* bunit = (const bf16x8*)&b_lds[ss & 1][0];
#pragma unroll
    for (int t = 0; t < 32; ++t)
      acc[t] = __builtin_amdgcn_mfma_f32_16x16x32_bf16(
          av, bunit[t * 64 + bbase], acc[t], 0, 0, 0);
    __syncthreads();   // drains prefetch vmcnt; readers of this buf done
  }

  // C layout: col(code-in-tile)=lane&15, row=4*(lane>>4)+reg (m89-verified).
  const unsigned long long gmask = 0xFFFFULL << (g * 16);
  const unsigned long long below = (1ULL << lane) - 1;
#pragma unroll
  for (int q = 0; q < 4; ++q) {
    float m = acc[0][q];
#pragma unroll
    for (int t = 1; t < 32; ++t) m = fminf(m, acc[t][q]);
#pragma unroll
    for (int off = 1; off < 16; off <<= 1)
      m = fminf(m, __shfl_xor(m, off, 64));
    const int r_loc = wv * 16 + 4 * g + q;
    const float thr = m + 1.6e-3f * sqrtf(s[rowbase + r_loc]) + 1e-3f;
#pragma unroll
    for (int t = 0; t < 32; ++t) {
      bool keep = (acc[t][q] <= thr);
      unsigned long long mask = __ballot(keep) & gmask;
      if (keep) {
        int prefix = __popcll(mask & below);
        int n = __popcll(mask);
        unsigned long long lowbit = mask & (0ULL - mask);
        int low = __popcll(lowbit - 1);
        int base = 0, qb = 0;
        if (lane == low) {
          base = atomicAdd(&cnt_lds[r_loc], n);
          int enq = CAP - base;
          enq = enq < 0 ? 0 : (enq > n ? n : enq);
          qb = enq > 0 ? atomicAdd(&q_cnt, enq) : 0;
        }
        base = __shfl(base, low, 64);
        qb = __shfl(qb, low, 64);
        if (base + prefix < CAP)
          lds_q[qb + prefix] =
              ((unsigned)(rowbase + r_loc) << 9) | (unsigned)(t * 16 + lx);
      }
    }
  }
  __syncthreads();

  // flush LDS queue to global (one atomic per block)
  if (tid == 0) {
    unsigned total = (unsigned)q_cnt;
    unsigned gb = atomicAdd(qn, total);
    gbase_s = gb;
    qof = (gb + total > qcap) ? 1 : 0;
  }
  __syncthreads();
  const unsigned gb = gbase_s;
  const int qc = q_cnt;
  if (!qof) {
    for (int i = tid; i < qc; i += 256) queue[gb + i] = lds_q[i];
  } else {
    for (int i = tid; i < qc; i += 256)
      if (gb + i < qcap) queue[gb + i] = 0xFFFFFFFFu;   // sentinel
    if (tid < 64) {                                     // whole block -> ovf
      unsigned p = atomicAdd(ovn, 1u);
      ovf[p] = (unsigned)(rowbase + tid);
    }
  }
  if (tid < 64 && cnt_lds[tid] > CAP) {                 // per-row overflow
    unsigned p = atomicAdd(ovn, 1u);
    ovf[p] = (unsigned)(rowbase + tid);
  }
}

// Exact rescore: ONE THREAD PER CANDIDATE. Bit-identical reference chain;
// per-row argmin resolved by atomicMin on key = ford(d)<<32 | code
// (lexicographic (d, code) -> first-index tie-break; order-independent).
__global__ __launch_bounds__(256) void rescore_kernel(
    const float* __restrict__ z, const float* __restrict__ cb,
    const float* __restrict__ s, const float* __restrict__ se,
    const unsigned* __restrict__ qn, const unsigned* __restrict__ queue,
    unsigned qcap, unsigned long long* __restrict__ rowkey) {
  unsigned nq = *qn;
  if (nq > qcap) nq = qcap;
  unsigned idx = blockIdx.x * 256 + threadIdx.x;
  if (idx >= nq) return;
  unsigned e = queue[idx];
  unsigned row = e >> 9;
  if (row >= M_ROWS) return;                  // sentinel
  int code = (int)(e & 511u);
  const float4* zr = (const float4*)(z + (size_t)row * DD);
  const float4* cr = (const float4*)(cb + (size_t)code * DD);
  float a = 0.0f;
#pragma unroll 8
  for (int k4 = 0; k4 < 64; ++k4) {
    float4 zf = zr[k4], cf = cr[k4];
    a = __fmaf_rn(zf.x, cf.x, a);
    a = __fmaf_rn(zf.y, cf.y, a);
    a = __fmaf_rn(zf.z, cf.z, a);
    a = __fmaf_rn(zf.w, cf.w, a);
  }
  float d = __fadd_rn(__fsub_rn(s[row], __fmul_rn(2.0f, a)), se[code]);
  unsigned long long key = ((unsigned long long)ford(d) << 32) | (unsigned)code;
  atomicMin(&rowkey[row], key);
}

// Overflow fallback: full 512-code exact scan, one wave per overflow row.
__global__ __launch_bounds__(256) void ovf_kernel(
    const float* __restrict__ z, const float* __restrict__ cb,
    const float* __restrict__ s, const float* __restrict__ se,
    const unsigned* __restrict__ ovn, const unsigned* __restrict__ ovf,
    unsigned long long* __restrict__ rowkey) {
  const int nov = (int)*ovn;
  const int lane = threadIdx.x & 63, wv = threadIdx.x >> 6;
  for (int i = blockIdx.x * 4 + wv; i < nov; i += gridDim.x * 4) {
    const int row = (int)ovf[i];
    const float4* zr = (const float4*)(z + (size_t)row * DD);
    const float s_r = s[row];
    float bd = INFINITY;
    int bi = INT_MAX;
#pragma unroll 1
    for (int j = 0; j < 8; ++j) {
      int code = lane + 64 * j;
      const float4* cr = (const float4*)(cb + (size_t)code * DD);
      float a = 0.0f;
#pragma unroll 4
      for (int k4 = 0; k4 < 64; ++k4) {
        float4 zf = zr[k4], cf = cr[k4];
        a = __fmaf_rn(zf.x, cf.x, a);
        a = __fmaf_rn(zf.y, cf.y, a);
        a = __fmaf_rn(zf.z, cf.z, a);
        a = __fmaf_rn(zf.w, cf.w, a);
      }
      float d = __fadd_rn(__fsub_rn(s_r, __fmul_rn(2.0f, a)), se[code]);
      if (d < bd || (d == bd && code < bi)) { bd = d; bi = code; }
    }
#pragma unroll
    for (int off = 1; off < 64; off <<= 1) {
      float od = __shfl_xor(bd, off, 64);
      int oi = __shfl_xor(bi, off, 64);
      if (od < bd || (od == bd && oi < bi)) { bd = od; bi = oi; }
    }
    if (lane == 0)
      atomicMin(&rowkey[row],
                ((unsigned long long)ford(bd) << 32) | (unsigned)bi);
  }
}

// Output: one wave per row; out0 = fl(z + fl(cb[idx]-z)), out1 = cb[idx].
__global__ __launch_bounds__(256) void output_kernel(
    const float* __restrict__ z, const float* __restrict__ cb,
    const unsigned long long* __restrict__ rowkey, float* __restrict__ out) {
  const int lane = threadIdx.x & 63, wv = threadIdx.x >> 6;
  const int r = blockIdx.x * 4 + wv;
  const int code = (int)(rowkey[r] & 0x1FFu);
  const float4* zr = (const float4*)(z + (size_t)r * DD);
  const float4* cr = (const float4*)(cb + (size_t)code * DD);
  float4 zv = zr[lane], cv = cr[lane];
  float4 o0;
  o0.x = __fadd_rn(zv.x, __fsub_rn(cv.x, zv.x));
  o0.y = __fadd_rn(zv.y, __fsub_rn(cv.y, zv.y));
  o0.z = __fadd_rn(zv.z, __fsub_rn(cv.z, zv.z));
  o0.w = __fadd_rn(zv.w, __fsub_rn(cv.w, zv.w));
  float4* out0 = (float4*)out;
  float4* out1 = out0 + (size_t)M_ROWS * 64;
  out0[(size_t)r * 64 + lane] = o0;
  out1[(size_t)r * 64 + lane] = cv;
}

extern "C" void kernel_launch(void* const* d_in, const int* in_sizes, int n_in,
                              void* d_out, int out_size, void* d_ws, size_t ws_size,
                              hipStream_t stream) {
  const float* z  = (const float*)d_in[0];   // [65536, 256]
  const float* cb = (const float*)d_in[1];   // [512, 256]
  float* out = (float*)d_out;

  // ws layout (bytes):
  //   s      [0,       262144)
  //   se     [262144,  264192)
  //   img    [264192,  559104)
  //   qn/ovn [559104,  559232)
  //   rowkey [559232,  1083520)
  //   ovf    [1083520, 1345664)
  //   queue  [1345664, 1345664 + qcap*4)
  char* w = (char*)d_ws;
  float* s  = (float*)w;
  float* se = (float*)(w + 262144);
  unsigned short* img = (unsigned short*)(w + 264192);
  unsigned* qn  = (unsigned*)(w + 559104);
  unsigned* ovn = (unsigned*)(w + 559108);
  unsigned long long* rowkey = (unsigned long long*)(w + 559232);
  unsigned* ovf = (unsigned*)(w + 1083520);
  unsigned* queue = (unsigned*)(w + 1345664);

  size_t qbytes = ws_size > 1345664 ? ws_size - 1345664 : 0;
  size_t qcap_s = qbytes / 4;
  size_t qmax = (size_t)M_ROWS * CAP;
  unsigned qcap = (unsigned)(qcap_s < qmax ? qcap_s : qmax);

  init_kernel<<<M_ROWS / 256, 256, 0, stream>>>(rowkey, qn, ovn);
  sumsq_kernel<<<M_ROWS / 256, 256, 0, stream>>>(z, s, M_ROWS);
  sumsq_kernel<<<KC / 256, 256, 0, stream>>>(cb, se, KC);
  build_img_kernel<<<(9 * KC * 4 + 255) / 256, 256, 0, stream>>>(cb, se, img);
  filter_kernel<<<M_ROWS / 64, 256, 0, stream>>>(z, img, s, qn, queue, qcap,
                                                 ovn, ovf);
  if (qcap > 0)
    rescore_kernel<<<(int)((qcap + 255) / 256), 256, 0, stream>>>(
        z, cb, s, se, qn, queue, qcap, rowkey);
  ovf_kernel<<<256, 256, 0, stream>>>(z, cb, s, se, ovn, ovf, rowkey);
  output_kernel<<<M_ROWS / 4, 256, 0, stream>>>(z, cb, rowkey, out);
}